// Round 3
// baseline (38687.112 us; speedup 1.0000x reference)
//
#include <hip/hip_runtime.h>
#include <hip/hip_fp16.h>

// Sizes fixed by the problem.
#define B_   64
#define T_   1024
#define H1_  128
#define H2_  256
#define TC_  256              // time-chunk for LSTM3/4
#define NCH  (T_ / TC_)       // 4 chunks
#define MCH  (B_ * TC_)       // 16384 rows per chunk per layer

typedef unsigned int  u32;
typedef unsigned short u16;

__device__ __forceinline__ float2 up2(u32 p) {            // 2 x fp16 -> 2 x fp32
    __half2 h = __builtin_bit_cast(__half2, p);
    return __half22float2(h);
}
__device__ __forceinline__ u32 pk2(float a, float b) {     // 2 x fp32 -> packed fp16
    __half2 h = __floats2half2_rn(a, b);
    return __builtin_bit_cast(u32, h);
}
__device__ __forceinline__ float hf(u16 u) { return __half2float(__builtin_bit_cast(__half, u)); }
__device__ __forceinline__ u16 fh(float f) { return __builtin_bit_cast(u16, __float2half(f)); }
__device__ __forceinline__ float sigf(float x) { return 1.0f / (1.0f + expf(-x)); }

// ---------------------------------------------------------------------------
// Phase B: LSTM1 + LSTM2 (H=128), persistent, fp32 weights in registers.
// grid = 128 (batch*2), block = 512 (one thread per gate column).
// Conv1d(SAME,k=4,CIN=1) folds into 4 FMAs/step. LSTM2 sees flip(x, features).
// amdgpu_waves_per_eu(2,2): LDS/grid already cap us at 1 block/CU (2 waves/EU);
// pin the allocator there so the ~160 live regs don't spill (r2: spill disaster).
// ---------------------------------------------------------------------------
__global__ __attribute__((amdgpu_waves_per_eu(2, 2))) __launch_bounds__(512)
void lstm_small(
    const float* __restrict__ X, const float* __restrict__ cw, const float* __restrict__ cb,
    const float* __restrict__ Wi1, const float* __restrict__ Wh1, const float* __restrict__ b1,
    const float* __restrict__ Wi2, const float* __restrict__ Wh2, const float* __restrict__ b2,
    u16* __restrict__ x12)
{
    const int blk = blockIdx.x;
    const int b = blk >> 1;
    const int layer = blk & 1;
    const int j = threadIdx.x;

    const float* Wi = layer ? Wi2 : Wi1;
    const float* Wh = layer ? Wh2 : Wh1;
    const float* bb = layer ? b2 : b1;

    float wi[16];
#pragma unroll
    for (int c = 0; c < 16; ++c) {
        int cc = layer ? (15 - c) : c;
        wi[c] = Wi[cc * 512 + j];
    }
    float wh[128];
#pragma unroll
    for (int k = 0; k < 128; ++k) wh[k] = Wh[k * 512 + j];

    float W4[4];
#pragma unroll
    for (int kk = 0; kk < 4; ++kk) {
        float s = 0.f;
#pragma unroll
        for (int c = 0; c < 16; ++c) s += cw[kk * 16 + c] * wi[c];
        W4[kk] = s;
    }
    float beff = bb[j];
#pragma unroll
    for (int c = 0; c < 16; ++c) beff += cb[c] * wi[c];

    __shared__ __align__(16) float hbuf[128];
    __shared__ float zbuf[512];
    if (j < 128) hbuf[j] = 0.f;
    float c_state = 0.f;

    const float* Xb = X + (size_t)b * T_;
    float xm1 = 0.f, x0 = Xb[0], xp1 = Xb[1], xp2 = Xb[2];
    __syncthreads();

    for (int t = 0; t < T_; ++t) {
        float z = beff + xm1 * W4[0] + x0 * W4[1] + xp1 * W4[2] + xp2 * W4[3];
#pragma unroll
        for (int k = 0; k < 128; k += 4) {
            float4 hv = *(const float4*)&hbuf[k];   // uniform address -> LDS broadcast
            z += hv.x * wh[k] + hv.y * wh[k + 1] + hv.z * wh[k + 2] + hv.w * wh[k + 3];
        }
        zbuf[j] = z;
        __syncthreads();
        if (j < 128) {
            float zi = zbuf[j], zf = zbuf[128 + j], zg = zbuf[256 + j], zo = zbuf[384 + j];
            c_state = sigf(zf) * c_state + sigf(zi) * tanhf(zg);
            float h = sigf(zo) * tanhf(c_state);
            hbuf[j] = h;
            x12[((size_t)b * T_ + t) * 256 + layer * 128 + j] = fh(h);
        }
        xm1 = x0; x0 = xp1; xp1 = xp2;
        xp2 = (t + 3 < T_) ? Xb[t + 3] : 0.f;
        __syncthreads();
    }
}

// ---------------------------------------------------------------------------
// Wh3/Wh4 (256 x 1024 fp32) -> packed fp16 pairs, layout [l][k2][j]:
//   wpk[l*131072 + k2*1024 + j] = half(Wh[2k2][j]) | half(Wh[2k2+1][j])<<16
// ---------------------------------------------------------------------------
__global__ void cvt_wh(const float* __restrict__ Wh3, const float* __restrict__ Wh4,
                       u32* __restrict__ wpk)
{
    int idx = blockIdx.x * 256 + threadIdx.x;   // < 262144
    int l = idx >> 17;
    int rem = idx & 131071;
    int k2 = rem >> 10;
    int j = rem & 1023;
    const float* W = l ? Wh4 : Wh3;
    wpk[idx] = pk2(W[(2 * k2) * 1024 + j], W[(2 * k2 + 1) * 1024 + j]);
}

// ---------------------------------------------------------------------------
// Tiled GEMM, 128x128 tile, 256 threads, 8x8/thread, K-tile 16. A is fp16.
// KREV: reverse B's K index (feature flip). CHUNK: A-row remap for time chunks.
// OUTMODE 0: out fp16 (acc+bias)    OUTMODE 1: out fp32 tanh(acc+bias)
// ---------------------------------------------------------------------------
template<int KREV, int OUTMODE, int CHUNK>
__global__ __launch_bounds__(256) void gemm128(
    const u16* __restrict__ A, const float* __restrict__ Bm,
    const float* __restrict__ bias, void* __restrict__ outv,
    int t0, int N, int K)
{
    __shared__ __align__(16) float Alds[16][132];
    __shared__ __align__(16) float Blds[16][128];
    const int tid = threadIdx.x;
    const int m0 = blockIdx.x * 128;
    const int n0 = blockIdx.y * 128;
    const int tm = tid >> 4, tn = tid & 15;
    const int ar = tid >> 1, ak = (tid & 1) * 8;
    const int bk = tid >> 4, bn = (tid & 15) * 8;

    int arow = m0 + ar;
    if (CHUNK) arow = (arow >> 8) * T_ + t0 + (arow & 255);

    float acc[8][8];
#pragma unroll
    for (int r = 0; r < 8; ++r)
#pragma unroll
        for (int c = 0; c < 8; ++c) acc[r][c] = 0.f;

    for (int k0 = 0; k0 < K; k0 += 16) {
        const u16* Ap = A + (size_t)arow * K + k0 + ak;
        uint4 u = *(const uint4*)Ap;
        float2 f0 = up2(u.x), f1 = up2(u.y), f2 = up2(u.z), f3 = up2(u.w);
        float av[8] = {f0.x, f0.y, f1.x, f1.y, f2.x, f2.y, f3.x, f3.y};

        int krow = KREV ? (K - 1 - (k0 + bk)) : (k0 + bk);
        const float* Bp = Bm + (size_t)krow * N + n0 + bn;
        float4 bv0 = *(const float4*)Bp;
        float4 bv1 = *(const float4*)(Bp + 4);
#pragma unroll
        for (int i = 0; i < 8; ++i) Alds[ak + i][ar] = av[i];
        *(float4*)&Blds[bk][bn] = bv0;
        *(float4*)&Blds[bk][bn + 4] = bv1;
        __syncthreads();
#pragma unroll
        for (int kk = 0; kk < 16; ++kk) {
            float a[8], bb8[8];
            *(float4*)a         = *(const float4*)&Alds[kk][tm * 8];
            *(float4*)(a + 4)   = *(const float4*)&Alds[kk][tm * 8 + 4];
            *(float4*)bb8       = *(const float4*)&Blds[kk][tn * 8];
            *(float4*)(bb8 + 4) = *(const float4*)&Blds[kk][tn * 8 + 4];
#pragma unroll
            for (int r = 0; r < 8; ++r)
#pragma unroll
                for (int c = 0; c < 8; ++c) acc[r][c] += a[r] * bb8[c];
        }
        __syncthreads();
    }

    float bv[8];
#pragma unroll
    for (int c = 0; c < 8; ++c) bv[c] = bias[n0 + tn * 8 + c];

    if (OUTMODE == 0) {
        u16* outp = (u16*)outv;
#pragma unroll
        for (int r = 0; r < 8; ++r) {
            u32 pk[4];
#pragma unroll
            for (int c2 = 0; c2 < 4; ++c2)
                pk[c2] = pk2(acc[r][2 * c2] + bv[2 * c2], acc[r][2 * c2 + 1] + bv[2 * c2 + 1]);
            uint4 st = make_uint4(pk[0], pk[1], pk[2], pk[3]);
            *(uint4*)(outp + (size_t)(m0 + tm * 8 + r) * N + n0 + tn * 8) = st;
        }
    } else {
        float* outp = (float*)outv;
#pragma unroll
        for (int r = 0; r < 8; ++r) {
            float v[8];
#pragma unroll
            for (int c = 0; c < 8; ++c) v[c] = tanhf(acc[r][c] + bv[c]);
            *(float4*)(outp + (size_t)(m0 + tm * 8 + r) * N + n0 + tn * 8)     = *(float4*)v;
            *(float4*)(outp + (size_t)(m0 + tm * 8 + r) * N + n0 + tn * 8 + 4) = *(float4*)(v + 4);
        }
    }
}

// ---------------------------------------------------------------------------
// Phase C: LSTM3 + LSTM4 (H=256) over one time chunk [t0, t0+TC_).
// fp16-packed weights: 96 packed u32/col in VGPRs + 32 packed u32/col in LDS.
// grid = 128 (batch*2), block = 512: thread i owns gate columns i and 512+i.
// (c,h) carried across chunks in `state`.
// amdgpu_waves_per_eu(2,2): 137 KB LDS caps at 1 block/CU anyway; pin the
// allocator at 2 waves/EU -> 256 VGPR budget so wA/wB (192 regs) stay resident.
// ---------------------------------------------------------------------------
__global__ __attribute__((amdgpu_waves_per_eu(2, 2))) __launch_bounds__(512)
void lstm_big(
    const u16* __restrict__ pre, const u32* __restrict__ wpk,
    float* __restrict__ state, u16* __restrict__ enc, int t0)
{
    const int blk = blockIdx.x;
    const int b = blk >> 1;
    const int layer = blk & 1;
    const int i = threadIdx.x;

    __shared__ __align__(16) float hbuf[256];
    __shared__ float zbuf[1024];
    __shared__ __align__(16) u32 wlds[512 * 66];   // 135168 B

    const u32* wp = wpk + (size_t)layer * 131072;  // [k2][j] packed fp16 pairs
    u32 wA[96], wB[96];
#pragma unroll
    for (int q = 0; q < 96; ++q) {
        wA[q] = wp[q * 1024 + i];
        wB[q] = wp[q * 1024 + 512 + i];
    }
#pragma unroll
    for (int q = 0; q < 32; ++q) {
        wlds[i * 66 + q]      = wp[(96 + q) * 1024 + i];
        wlds[i * 66 + 32 + q] = wp[(96 + q) * 1024 + 512 + i];
    }
    float* st = state + ((size_t)layer * B_ + b) * 512;
    float c_state = 0.f;
    if (t0 == 0) {
        if (i < 256) hbuf[i] = 0.f;
    } else {
        if (i < 256) { c_state = st[i]; hbuf[i] = st[256 + i]; }
    }
    __syncthreads();

    const u16* prow = pre + (size_t)(layer * MCH + b * TC_) * 1024;
    u16* encrow = enc + ((size_t)b * T_ + t0) * 512 + layer * 256;

    for (int tt = 0; tt < TC_; ++tt, prow += 1024, encrow += 512) {
        float z0 = hf(prow[i]);
        float z1 = hf(prow[512 + i]);
#pragma unroll
        for (int m = 0; m < 48; ++m) {          // k = 4m..4m+3 from registers
            float4 hv = *(const float4*)&hbuf[4 * m];
            float2 a0 = up2(wA[2 * m]), a1 = up2(wA[2 * m + 1]);
            z0 += a0.x * hv.x + a0.y * hv.y + a1.x * hv.z + a1.y * hv.w;
            float2 c0 = up2(wB[2 * m]), c1 = up2(wB[2 * m + 1]);
            z1 += c0.x * hv.x + c0.y * hv.y + c1.x * hv.z + c1.y * hv.w;
        }
#pragma unroll
        for (int m = 48; m < 64; ++m) {         // k = 4m..4m+3 from LDS
            float4 hv = *(const float4*)&hbuf[4 * m];
            int qq = 2 * m - 96;
            uint2 pa = *(const uint2*)&wlds[i * 66 + qq];
            uint2 pb = *(const uint2*)&wlds[i * 66 + 32 + qq];
            float2 a0 = up2(pa.x), a1 = up2(pa.y);
            float2 c0 = up2(pb.x), c1 = up2(pb.y);
            z0 += a0.x * hv.x + a0.y * hv.y + a1.x * hv.z + a1.y * hv.w;
            z1 += c0.x * hv.x + c0.y * hv.y + c1.x * hv.z + c1.y * hv.w;
        }
        zbuf[i] = z0;
        zbuf[512 + i] = z1;
        __syncthreads();
        if (i < 256) {
            float zi = zbuf[i], zf = zbuf[256 + i], zg = zbuf[512 + i], zo = zbuf[768 + i];
            c_state = sigf(zf) * c_state + sigf(zi) * tanhf(zg);
            float h = sigf(zo) * tanhf(c_state);
            hbuf[i] = h;
            encrow[i] = fh(h);
        }
        __syncthreads();
    }
    if (i < 256) { st[i] = c_state; st[256 + i] = hbuf[i]; }
}

// ---------------------------------------------------------------------------
// Attention pooling + head, one workgroup per batch.
// ---------------------------------------------------------------------------
__global__ __launch_bounds__(256) void attn_head(
    const float* __restrict__ S1, const u16* __restrict__ enc,
    const float* __restrict__ attV, const float* __restrict__ attVb,
    const float* __restrict__ d1W, const float* __restrict__ d1b,
    const float* __restrict__ d2W, const float* __restrict__ d2b,
    float* __restrict__ out)
{
    const int b = blockIdx.x;
    const int tid = threadIdx.x;
    const int lane = tid & 63, w = tid >> 6;

    __shared__ float sb[1024];
    __shared__ float red[32];
    __shared__ __align__(16) float ctx[512];
    __shared__ float h1s[128];

    float av0 = attV[lane], av1 = attV[64 + lane];
    const float* S1b = S1 + (size_t)b * T_ * 128;
    for (int it = 0; it < 256; ++it) {
        int t = it * 4 + w;
        const float* row = S1b + (size_t)t * 128;
        float p = row[lane] * av0 + row[64 + lane] * av1;
#pragma unroll
        for (int off = 32; off > 0; off >>= 1) p += __shfl_down(p, off);
        if (lane == 0) sb[t] = p + attVb[0];
    }
    __syncthreads();

    float mx = -3.0e38f;
#pragma unroll
    for (int q = 0; q < 4; ++q) mx = fmaxf(mx, sb[tid + 256 * q]);
#pragma unroll
    for (int off = 32; off > 0; off >>= 1) mx = fmaxf(mx, __shfl_down(mx, off));
    if (lane == 0) red[w] = mx;
    __syncthreads();
    if (tid == 0) red[8] = fmaxf(fmaxf(red[0], red[1]), fmaxf(red[2], red[3]));
    __syncthreads();
    float bm = red[8];
    float s = 0.f;
#pragma unroll
    for (int q = 0; q < 4; ++q) {
        float e = expf(sb[tid + 256 * q] - bm);
        sb[tid + 256 * q] = e;
        s += e;
    }
#pragma unroll
    for (int off = 32; off > 0; off >>= 1) s += __shfl_down(s, off);
    if (lane == 0) red[16 + w] = s;
    __syncthreads();
    if (tid == 0) red[24] = 1.0f / (red[16] + red[17] + red[18] + red[19]);
    __syncthreads();
    float inv = red[24];
#pragma unroll
    for (int q = 0; q < 4; ++q) sb[tid + 256 * q] *= inv;
    __syncthreads();

    const u16* encb = enc + (size_t)b * T_ * 512;
    float a0 = 0.f, a1 = 0.f;
    for (int t = 0; t < T_; ++t) {
        float wt = sb[t];
        a0 += wt * hf(encb[(size_t)t * 512 + tid]);
        a1 += wt * hf(encb[(size_t)t * 512 + 256 + tid]);
    }
    ctx[tid] = a0;
    ctx[256 + tid] = a1;
    __syncthreads();

    if (tid < 128) {
        float s1 = d1b[tid];
        for (int k = 0; k < 512; ++k) s1 += ctx[k] * d1W[k * 128 + tid];
        h1s[tid] = tanhf(s1);
    }
    __syncthreads();
    if (tid < 128) {
        float p = h1s[tid] * d2W[tid];
#pragma unroll
        for (int off = 32; off > 0; off >>= 1) p += __shfl_down(p, off);
        if ((tid & 63) == 0) red[28 + (tid >> 6)] = p;
    }
    __syncthreads();
    if (tid == 0) out[b] = red[28] + red[29] + d2b[0];
}

// ---------------------------------------------------------------------------
extern "C" void kernel_launch(void* const* d_in, const int* in_sizes, int n_in,
                              void* d_out, int out_size, void* d_ws, size_t ws_size,
                              hipStream_t stream)
{
    const float* X    = (const float*)d_in[0];
    const float* cw   = (const float*)d_in[1];
    const float* cb   = (const float*)d_in[2];
    const float* Wi1  = (const float*)d_in[3];
    const float* Wh1  = (const float*)d_in[4];
    const float* b1   = (const float*)d_in[5];
    const float* Wi2  = (const float*)d_in[6];
    const float* Wh2  = (const float*)d_in[7];
    const float* b2   = (const float*)d_in[8];
    const float* Wi3  = (const float*)d_in[9];
    const float* Wh3  = (const float*)d_in[10];
    const float* b3   = (const float*)d_in[11];
    const float* Wi4  = (const float*)d_in[12];
    const float* Wh4  = (const float*)d_in[13];
    const float* b4   = (const float*)d_in[14];
    const float* attW = (const float*)d_in[15];
    const float* attWb= (const float*)d_in[16];
    const float* attV = (const float*)d_in[17];
    const float* attVb= (const float*)d_in[18];
    const float* d1W  = (const float*)d_in[19];
    const float* d1b  = (const float*)d_in[20];
    const float* d2W  = (const float*)d_in[21];
    const float* d2b  = (const float*)d_in[22];
    float* out = (float*)d_out;

    // workspace layout (total 169,082,880 B ~ 161.3 MiB):
    char* w = (char*)d_ws;
    u16*   x12  = (u16*)w;                          // 64*1024*256*2      = 33,554,432
    u16*   pre  = (u16*)(w + 33554432);             // 2*16384*1024*2     = 67,108,864 (per chunk)
    u16*   enc  = (u16*)(w + 100663296);            // 64*1024*512*2      = 67,108,864
    u32*   wpk  = (u32*)(w + 167772160);            // 2*128*1024*4       =  1,048,576
    float* state= (float*)(w + 168820736);          // 2*64*512*4         =    262,144
    float* S1   = (float*)(w + 33554432);           // 65536*128*4 = 32 MiB, aliases pre (dead)

    lstm_small<<<128, 512, 0, stream>>>(X, cw, cb, Wi1, Wh1, b1, Wi2, Wh2, b2, x12);
    cvt_wh<<<1024, 256, 0, stream>>>(Wh3, Wh4, wpk);

    for (int c = 0; c < NCH; ++c) {
        int t0 = c * TC_;
        gemm128<0, 0, 1><<<dim3(128, 8), 256, 0, stream>>>(x12, Wi3, b3, pre, t0, 1024, 256);
        gemm128<1, 0, 1><<<dim3(128, 8), 256, 0, stream>>>(x12, Wi4, b4, pre + (size_t)MCH * 1024, t0, 1024, 256);
        lstm_big<<<128, 512, 0, stream>>>(pre, wpk, state, enc, t0);
    }

    gemm128<0, 1, 0><<<dim3(512, 1), 256, 0, stream>>>(enc, attW, attWb, S1, 0, 128, 512);
    attn_head<<<64, 256, 0, stream>>>(S1, enc, attV, attVb, d1W, d1b, d2W, d2b, out);
}

// Round 4
// 4031.862 us; speedup vs baseline: 9.5953x; 9.5953x over previous
//
#include <hip/hip_runtime.h>
#include <hip/hip_fp16.h>

// Sizes fixed by the problem.
#define B_   64
#define T_   1024
#define H1_  128
#define H2_  256
#define TC_  256              // time-chunk for LSTM3/4
#define NCH  (T_ / TC_)       // 4 chunks
#define MCH  (B_ * TC_)       // 16384 rows per chunk per layer

#define WREG 92               // lstm_big: packed weight pairs in VGPRs per thread
#define WLDS 36               // lstm_big: packed weight pairs in LDS per thread

typedef unsigned int  u32;
typedef unsigned short u16;
typedef _Float16 half2_t __attribute__((ext_vector_type(2)));

__device__ __forceinline__ float fdot2(u32 w, u32 h, float acc) {
    // v_dot2_f32_f16: acc += w.lo*h.lo + w.hi*h.hi (fp32 accumulate)
    return __builtin_amdgcn_fdot2(__builtin_bit_cast(half2_t, w),
                                  __builtin_bit_cast(half2_t, h), acc, false);
}
__device__ __forceinline__ float2 up2(u32 p) {
    __half2 h = __builtin_bit_cast(__half2, p);
    return __half22float2(h);
}
__device__ __forceinline__ u32 pk2(float a, float b) {
    __half2 h = __floats2half2_rn(a, b);
    return __builtin_bit_cast(u32, h);
}
__device__ __forceinline__ float hf(u16 u) { return __half2float(__builtin_bit_cast(__half, u)); }
__device__ __forceinline__ u16 fh(float f) { return __builtin_bit_cast(u16, __float2half(f)); }
__device__ __forceinline__ float sigf(float x) { return 1.0f / (1.0f + expf(-x)); }

// ---------------------------------------------------------------------------
// Phase B: LSTM1 + LSTM2 (H=128). grid=128 (batch*2), block=512 (1 gate col).
// Wh packed fp16 in 64 VGPRs/thread; h packed fp16 in LDS; fdot2 inner loop.
// Conv1d(SAME,k=4,CIN=1) folds into 4 FMAs/step. LSTM2 sees flip(x, features).
// ---------------------------------------------------------------------------
__global__ __launch_bounds__(512) void lstm_small(
    const float* __restrict__ X, const float* __restrict__ cw, const float* __restrict__ cb,
    const float* __restrict__ Wi1, const float* __restrict__ Wh1, const float* __restrict__ b1,
    const float* __restrict__ Wi2, const float* __restrict__ Wh2, const float* __restrict__ b2,
    u16* __restrict__ x12)
{
    const int blk = blockIdx.x;
    const int b = blk >> 1;
    const int layer = blk & 1;
    const int j = threadIdx.x;

    const float* Wi = layer ? Wi2 : Wi1;
    const float* Wh = layer ? Wh2 : Wh1;
    const float* bb = layer ? b2 : b1;

    // fold conv into 4 taps + bias
    float W4[4];
#pragma unroll
    for (int kk = 0; kk < 4; ++kk) {
        float s = 0.f;
#pragma unroll
        for (int c = 0; c < 16; ++c) {
            int cc = layer ? (15 - c) : c;
            s += cw[kk * 16 + c] * Wi[cc * 512 + j];
        }
        W4[kk] = s;
    }
    float beff = bb[j];
#pragma unroll
    for (int c = 0; c < 16; ++c) {
        int cc = layer ? (15 - c) : c;
        beff += cb[c] * Wi[cc * 512 + j];
    }

    // packed fp16 recurrent weights: pair p = (Wh[2p][j], Wh[2p+1][j])
    u32 whp[64];
#pragma unroll
    for (int p = 0; p < 64; ++p)
        whp[p] = pk2(Wh[(2 * p) * 512 + j], Wh[(2 * p + 1) * 512 + j]);

    __shared__ __align__(16) u32 hbuf_pk[64];   // 128 h as packed fp16
    __shared__ float zbuf[512];
    u16* hb16 = (u16*)hbuf_pk;
    if (j < 128) hb16[j] = 0;
    float c_state = 0.f;

    const float* Xb = X + (size_t)b * T_;
    float xm1 = 0.f, x0 = Xb[0], xp1 = Xb[1], xp2 = Xb[2];
    __syncthreads();

    const uint4* hp4 = (const uint4*)hbuf_pk;
    for (int t = 0; t < T_; ++t) {
        float za = beff + xm1 * W4[0] + x0 * W4[1] + xp1 * W4[2] + xp2 * W4[3];
        float zb = 0.f, zc = 0.f, zd = 0.f;
#pragma unroll
        for (int m = 0; m < 16; ++m) {
            uint4 hh = hp4[m];
            za = fdot2(whp[4 * m + 0], hh.x, za);
            zb = fdot2(whp[4 * m + 1], hh.y, zb);
            zc = fdot2(whp[4 * m + 2], hh.z, zc);
            zd = fdot2(whp[4 * m + 3], hh.w, zd);
        }
        float z = (za + zb) + (zc + zd);
        // apply own gate nonlinearity (wave-uniform branch): g-gate is [256,384)
        zbuf[j] = (j >= 256 && j < 384) ? tanhf(z) : sigf(z);
        __syncthreads();
        if (j < 128) {
            float gi = zbuf[j], gf = zbuf[128 + j], gg = zbuf[256 + j], go = zbuf[384 + j];
            c_state = gf * c_state + gi * gg;
            float h = go * tanhf(c_state);
            hb16[j] = fh(h);
            x12[((size_t)b * T_ + t) * 256 + layer * 128 + j] = fh(h);
        }
        xm1 = x0; x0 = xp1; xp1 = xp2;
        xp2 = (t + 3 < T_) ? Xb[t + 3] : 0.f;
        __syncthreads();
    }
}

// ---------------------------------------------------------------------------
// Wh3/Wh4 (256 x 1024 fp32) -> packed fp16 pairs, layout [l][k2][j]:
//   wpk[l*131072 + k2*1024 + j] = half(Wh[2k2][j]) | half(Wh[2k2+1][j])<<16
// ---------------------------------------------------------------------------
__global__ void cvt_wh(const float* __restrict__ Wh3, const float* __restrict__ Wh4,
                       u32* __restrict__ wpk)
{
    int idx = blockIdx.x * 256 + threadIdx.x;   // < 262144
    int l = idx >> 17;
    int rem = idx & 131071;
    int k2 = rem >> 10;
    int j = rem & 1023;
    const float* W = l ? Wh4 : Wh3;
    wpk[idx] = pk2(W[(2 * k2) * 1024 + j], W[(2 * k2 + 1) * 1024 + j]);
}

// ---------------------------------------------------------------------------
// Tiled GEMM, 128x128 tile, 256 threads, 8x8/thread, K-tile 16. A is fp16.
// KREV: reverse B's K index (feature flip). CHUNK: A-row remap for time chunks.
// OUTMODE 0: out fp16 (acc+bias)    OUTMODE 1: out fp32 tanh(acc+bias)
// ---------------------------------------------------------------------------
template<int KREV, int OUTMODE, int CHUNK>
__global__ __launch_bounds__(256) void gemm128(
    const u16* __restrict__ A, const float* __restrict__ Bm,
    const float* __restrict__ bias, void* __restrict__ outv,
    int t0, int N, int K)
{
    __shared__ __align__(16) float Alds[16][132];
    __shared__ __align__(16) float Blds[16][128];
    const int tid = threadIdx.x;
    const int m0 = blockIdx.x * 128;
    const int n0 = blockIdx.y * 128;
    const int tm = tid >> 4, tn = tid & 15;
    const int ar = tid >> 1, ak = (tid & 1) * 8;
    const int bk = tid >> 4, bn = (tid & 15) * 8;

    int arow = m0 + ar;
    if (CHUNK) arow = (arow >> 8) * T_ + t0 + (arow & 255);

    float acc[8][8];
#pragma unroll
    for (int r = 0; r < 8; ++r)
#pragma unroll
        for (int c = 0; c < 8; ++c) acc[r][c] = 0.f;

    for (int k0 = 0; k0 < K; k0 += 16) {
        const u16* Ap = A + (size_t)arow * K + k0 + ak;
        uint4 u = *(const uint4*)Ap;
        float2 f0 = up2(u.x), f1 = up2(u.y), f2 = up2(u.z), f3 = up2(u.w);
        float av[8] = {f0.x, f0.y, f1.x, f1.y, f2.x, f2.y, f3.x, f3.y};

        int krow = KREV ? (K - 1 - (k0 + bk)) : (k0 + bk);
        const float* Bp = Bm + (size_t)krow * N + n0 + bn;
        float4 bv0 = *(const float4*)Bp;
        float4 bv1 = *(const float4*)(Bp + 4);
#pragma unroll
        for (int i = 0; i < 8; ++i) Alds[ak + i][ar] = av[i];
        *(float4*)&Blds[bk][bn] = bv0;
        *(float4*)&Blds[bk][bn + 4] = bv1;
        __syncthreads();
#pragma unroll
        for (int kk = 0; kk < 16; ++kk) {
            float a[8], bb8[8];
            *(float4*)a         = *(const float4*)&Alds[kk][tm * 8];
            *(float4*)(a + 4)   = *(const float4*)&Alds[kk][tm * 8 + 4];
            *(float4*)bb8       = *(const float4*)&Blds[kk][tn * 8];
            *(float4*)(bb8 + 4) = *(const float4*)&Blds[kk][tn * 8 + 4];
#pragma unroll
            for (int r = 0; r < 8; ++r)
#pragma unroll
                for (int c = 0; c < 8; ++c) acc[r][c] += a[r] * bb8[c];
        }
        __syncthreads();
    }

    float bv[8];
#pragma unroll
    for (int c = 0; c < 8; ++c) bv[c] = bias[n0 + tn * 8 + c];

    if (OUTMODE == 0) {
        u16* outp = (u16*)outv;
#pragma unroll
        for (int r = 0; r < 8; ++r) {
            u32 pk[4];
#pragma unroll
            for (int c2 = 0; c2 < 4; ++c2)
                pk[c2] = pk2(acc[r][2 * c2] + bv[2 * c2], acc[r][2 * c2 + 1] + bv[2 * c2 + 1]);
            uint4 st = make_uint4(pk[0], pk[1], pk[2], pk[3]);
            *(uint4*)(outp + (size_t)(m0 + tm * 8 + r) * N + n0 + tn * 8) = st;
        }
    } else {
        float* outp = (float*)outv;
#pragma unroll
        for (int r = 0; r < 8; ++r) {
            float v[8];
#pragma unroll
            for (int c = 0; c < 8; ++c) v[c] = tanhf(acc[r][c] + bv[c]);
            *(float4*)(outp + (size_t)(m0 + tm * 8 + r) * N + n0 + tn * 8)     = *(float4*)v;
            *(float4*)(outp + (size_t)(m0 + tm * 8 + r) * N + n0 + tn * 8 + 4) = *(float4*)(v + 4);
        }
    }
}

// ---------------------------------------------------------------------------
// Phase C: LSTM3 + LSTM4 (H=256) over one time chunk [t0, t0+TC_).
// grid=128 (batch*2), block=1024: thread j owns gate column j (of 1024).
// Per thread 128 packed fp16 weight pairs: WREG=92 in VGPRs, WLDS=36 in LDS
// (uint2-interleaved [q2][j]). h packed fp16 in LDS; 128 fdot2/step.
// Fits the compiler's 128-VGPR cap -> no scratch spill (r2/r3 disaster).
// ---------------------------------------------------------------------------
__global__ __launch_bounds__(1024) void lstm_big(
    const u16* __restrict__ pre, const u32* __restrict__ wpk,
    float* __restrict__ state, u16* __restrict__ enc, int t0)
{
    const int blk = blockIdx.x;
    const int b = blk >> 1;
    const int layer = blk & 1;
    const int j = threadIdx.x;

    __shared__ u32 wlds[WLDS * 1024];           // 147456 B, uint2 pairs [q2][1024]
    __shared__ __align__(16) u32 hbuf_pk[128];  // 256 h as packed fp16
    __shared__ float zbuf[1024];

    const u32* wp = wpk + (size_t)layer * 131072;  // [k2][j] packed fp16 pairs
    u32 wreg[WREG];
#pragma unroll
    for (int q = 0; q < WREG; ++q) wreg[q] = wp[q * 1024 + j];
    uint2* wl = (uint2*)wlds;
#pragma unroll
    for (int q2 = 0; q2 < WLDS / 2; ++q2)
        wl[q2 * 1024 + j] = make_uint2(wp[(WREG + 2 * q2) * 1024 + j],
                                       (WREG + 2 * q2 + 1 < 128) ? wp[(WREG + 2 * q2 + 1) * 1024 + j] : 0u);

    float* st = state + ((size_t)layer * B_ + b) * 512;
    u16* hb16 = (u16*)hbuf_pk;
    float c_state = 0.f, h_last = 0.f;
    if (j < 256) {
        float h0 = (t0 == 0) ? 0.f : st[256 + j];
        c_state = (t0 == 0) ? 0.f : st[j];
        hb16[j] = fh(h0);
        h_last = h0;
    }
    __syncthreads();

    const u16* prow = pre + (size_t)(layer * MCH + b * TC_) * 1024;
    u16* encrow = enc + ((size_t)b * T_ + t0) * 512 + layer * 256;
    const uint4* hp4 = (const uint4*)hbuf_pk;

    for (int tt = 0; tt < TC_; ++tt, prow += 1024, encrow += 512) {
        float za = hf(prow[j]), zb = 0.f, zc = 0.f, zd = 0.f;
#pragma unroll
        for (int m = 0; m < WREG / 4; ++m) {       // pairs 0..91 from registers
            uint4 hh = hp4[m];
            za = fdot2(wreg[4 * m + 0], hh.x, za);
            zb = fdot2(wreg[4 * m + 1], hh.y, zb);
            zc = fdot2(wreg[4 * m + 2], hh.z, zc);
            zd = fdot2(wreg[4 * m + 3], hh.w, zd);
        }
#pragma unroll
        for (int m = 0; m < WLDS / 4; ++m) {       // pairs 92..127 from LDS
            uint4 hh = hp4[WREG / 4 + m];
            uint2 w0 = wl[(2 * m + 0) * 1024 + j];
            uint2 w1 = wl[(2 * m + 1) * 1024 + j];
            za = fdot2(w0.x, hh.x, za);
            zb = fdot2(w0.y, hh.y, zb);
            zc = fdot2(w1.x, hh.z, zc);
            zd = fdot2(w1.y, hh.w, zd);
        }
        float z = (za + zb) + (zc + zd);
        // own-gate nonlinearity, wave-uniform branch: g-gate is [512,768)
        zbuf[j] = (j >= 512 && j < 768) ? tanhf(z) : sigf(z);
        __syncthreads();
        if (j < 256) {
            float gi = zbuf[j], gf = zbuf[256 + j], gg = zbuf[512 + j], go = zbuf[768 + j];
            c_state = gf * c_state + gi * gg;
            float h = go * tanhf(c_state);
            hb16[j] = fh(h);
            encrow[j] = fh(h);
            h_last = h;
        }
        __syncthreads();
    }
    if (j < 256) { st[j] = c_state; st[256 + j] = h_last; }
}

// ---------------------------------------------------------------------------
// Attention pooling + head, one workgroup per batch.
// ---------------------------------------------------------------------------
__global__ __launch_bounds__(256) void attn_head(
    const float* __restrict__ S1, const u16* __restrict__ enc,
    const float* __restrict__ attV, const float* __restrict__ attVb,
    const float* __restrict__ d1W, const float* __restrict__ d1b,
    const float* __restrict__ d2W, const float* __restrict__ d2b,
    float* __restrict__ out)
{
    const int b = blockIdx.x;
    const int tid = threadIdx.x;
    const int lane = tid & 63, w = tid >> 6;

    __shared__ float sb[1024];
    __shared__ float red[32];
    __shared__ __align__(16) float ctx[512];
    __shared__ float h1s[128];

    float av0 = attV[lane], av1 = attV[64 + lane];
    const float* S1b = S1 + (size_t)b * T_ * 128;
    for (int it = 0; it < 256; ++it) {
        int t = it * 4 + w;
        const float* row = S1b + (size_t)t * 128;
        float p = row[lane] * av0 + row[64 + lane] * av1;
#pragma unroll
        for (int off = 32; off > 0; off >>= 1) p += __shfl_down(p, off);
        if (lane == 0) sb[t] = p + attVb[0];
    }
    __syncthreads();

    float mx = -3.0e38f;
#pragma unroll
    for (int q = 0; q < 4; ++q) mx = fmaxf(mx, sb[tid + 256 * q]);
#pragma unroll
    for (int off = 32; off > 0; off >>= 1) mx = fmaxf(mx, __shfl_down(mx, off));
    if (lane == 0) red[w] = mx;
    __syncthreads();
    if (tid == 0) red[8] = fmaxf(fmaxf(red[0], red[1]), fmaxf(red[2], red[3]));
    __syncthreads();
    float bm = red[8];
    float s = 0.f;
#pragma unroll
    for (int q = 0; q < 4; ++q) {
        float e = expf(sb[tid + 256 * q] - bm);
        sb[tid + 256 * q] = e;
        s += e;
    }
#pragma unroll
    for (int off = 32; off > 0; off >>= 1) s += __shfl_down(s, off);
    if (lane == 0) red[16 + w] = s;
    __syncthreads();
    if (tid == 0) red[24] = 1.0f / (red[16] + red[17] + red[18] + red[19]);
    __syncthreads();
    float inv = red[24];
#pragma unroll
    for (int q = 0; q < 4; ++q) sb[tid + 256 * q] *= inv;
    __syncthreads();

    const u16* encb = enc + (size_t)b * T_ * 512;
    float a0 = 0.f, a1 = 0.f;
    for (int t = 0; t < T_; ++t) {
        float wt = sb[t];
        a0 += wt * hf(encb[(size_t)t * 512 + tid]);
        a1 += wt * hf(encb[(size_t)t * 512 + 256 + tid]);
    }
    ctx[tid] = a0;
    ctx[256 + tid] = a1;
    __syncthreads();

    if (tid < 128) {
        float s1 = d1b[tid];
        for (int k = 0; k < 512; ++k) s1 += ctx[k] * d1W[k * 128 + tid];
        h1s[tid] = tanhf(s1);
    }
    __syncthreads();
    if (tid < 128) {
        float p = h1s[tid] * d2W[tid];
#pragma unroll
        for (int off = 32; off > 0; off >>= 1) p += __shfl_down(p, off);
        if ((tid & 63) == 0) red[28 + (tid >> 6)] = p;
    }
    __syncthreads();
    if (tid == 0) out[b] = red[28] + red[29] + d2b[0];
}

// ---------------------------------------------------------------------------
extern "C" void kernel_launch(void* const* d_in, const int* in_sizes, int n_in,
                              void* d_out, int out_size, void* d_ws, size_t ws_size,
                              hipStream_t stream)
{
    const float* X    = (const float*)d_in[0];
    const float* cw   = (const float*)d_in[1];
    const float* cb   = (const float*)d_in[2];
    const float* Wi1  = (const float*)d_in[3];
    const float* Wh1  = (const float*)d_in[4];
    const float* b1   = (const float*)d_in[5];
    const float* Wi2  = (const float*)d_in[6];
    const float* Wh2  = (const float*)d_in[7];
    const float* b2   = (const float*)d_in[8];
    const float* Wi3  = (const float*)d_in[9];
    const float* Wh3  = (const float*)d_in[10];
    const float* b3   = (const float*)d_in[11];
    const float* Wi4  = (const float*)d_in[12];
    const float* Wh4  = (const float*)d_in[13];
    const float* b4   = (const float*)d_in[14];
    const float* attW = (const float*)d_in[15];
    const float* attWb= (const float*)d_in[16];
    const float* attV = (const float*)d_in[17];
    const float* attVb= (const float*)d_in[18];
    const float* d1W  = (const float*)d_in[19];
    const float* d1b  = (const float*)d_in[20];
    const float* d2W  = (const float*)d_in[21];
    const float* d2b  = (const float*)d_in[22];
    float* out = (float*)d_out;

    // workspace layout (total 169,082,880 B ~ 161.3 MiB):
    char* w = (char*)d_ws;
    u16*   x12  = (u16*)w;                          // 64*1024*256*2      = 33,554,432
    u16*   pre  = (u16*)(w + 33554432);             // 2*16384*1024*2     = 67,108,864 (per chunk)
    u16*   enc  = (u16*)(w + 100663296);            // 64*1024*512*2      = 67,108,864
    u32*   wpk  = (u32*)(w + 167772160);            // 2*128*1024*4       =  1,048,576
    float* state= (float*)(w + 168820736);          // 2*64*512*4         =    262,144
    float* S1   = (float*)(w + 33554432);           // 65536*128*4 = 32 MiB, aliases pre (dead)

    lstm_small<<<128, 512, 0, stream>>>(X, cw, cb, Wi1, Wh1, b1, Wi2, Wh2, b2, x12);
    cvt_wh<<<1024, 256, 0, stream>>>(Wh3, Wh4, wpk);

    for (int c = 0; c < NCH; ++c) {
        int t0 = c * TC_;
        gemm128<0, 0, 1><<<dim3(128, 8), 256, 0, stream>>>(x12, Wi3, b3, pre, t0, 1024, 256);
        gemm128<1, 0, 1><<<dim3(128, 8), 256, 0, stream>>>(x12, Wi4, b4, pre + (size_t)MCH * 1024, t0, 1024, 256);
        lstm_big<<<128, 1024, 0, stream>>>(pre, wpk, state, enc, t0);
    }

    gemm128<0, 1, 0><<<dim3(512, 1), 256, 0, stream>>>(enc, attW, attWb, S1, 0, 128, 512);
    attn_head<<<64, 256, 0, stream>>>(S1, enc, attV, attVb, d1W, d1b, d2W, d2b, out);
}